// Round 8
// baseline (3598.680 us; speedup 1.0000x reference)
//
#include <hip/hip_runtime.h>
#include <cstdint>

typedef __attribute__((ext_vector_type(8))) short bf16x8;
typedef __attribute__((ext_vector_type(4))) float f32x4;

#define AS1 __attribute__((address_space(1)))
#define AS3 __attribute__((address_space(3)))

__device__ __forceinline__ unsigned short f2bf(float f) {
  unsigned int u = __builtin_bit_cast(unsigned int, f);
  return (unsigned short)((u + 0x7fffu + ((u >> 16) & 1u)) >> 16);
}
__device__ __forceinline__ float bf2f(unsigned short h) {
  unsigned int u = ((unsigned int)h) << 16;
  return __builtin_bit_cast(float, u);
}
__device__ __forceinline__ float sigm(float x) { return 1.f / (1.f + __expf(-x)); }
__device__ __forceinline__ float tanh_f(float x) {
  float e = __expf(2.f * x);          // inf-safe: e=inf -> 1, e=0 -> -1
  return 1.f - 2.f / (e + 1.f);
}
__device__ __forceinline__ void gload16(const void* g, void* l) {
  __builtin_amdgcn_global_load_lds((const AS1 unsigned int*)g, (AS3 unsigned int*)l, 16, 0, 0);
}
// XOR-swizzle for [rows][64]-bf16 tiles (step kernel only; the BK=32 xproj
// layout reads contiguous 1KB rows per fragment -> bandwidth-optimal, linear).
__device__ __forceinline__ int swz(int e) { return e ^ (((e >> 6) & 7) << 3); }

// ---------------- setup / conversion kernels ----------------

__global__ __launch_bounds__(256) void conv_wh_kernel(
    const float4* __restrict__ w0, const float4* __restrict__ w1,
    const float4* __restrict__ w2, const float4* __restrict__ w3,
    unsigned long long* __restrict__ dst) {
  int i = blockIdx.x * 256 + threadIdx.x;           // 0 .. 1M-1 (float4 units)
  int g = i >> 18;                                  // 262144 float4 per matrix
  const float4* s = g == 0 ? w0 : g == 1 ? w1 : g == 2 ? w2 : w3;
  float4 v = s[i & 0x3FFFF];
  unsigned long long p = (unsigned long long)f2bf(v.x) |
                         ((unsigned long long)f2bf(v.y) << 16) |
                         ((unsigned long long)f2bf(v.z) << 32) |
                         ((unsigned long long)f2bf(v.w) << 48);
  dst[i] = p;
}

__global__ __launch_bounds__(256) void conv_wiT_kernel(
    const float* __restrict__ w0, const float* __restrict__ w1,
    const float* __restrict__ w2, const float* __restrict__ w3,
    unsigned short* __restrict__ dst) {
  __shared__ unsigned short ls[64][72];
  int bid = blockIdx.x;                 // 0..1023 : 4 gates x 16x16 tiles
  int g = bid >> 8;
  int t2 = bid & 255;
  int tj = t2 & 15, tk = t2 >> 4;
  const float* W = g == 0 ? w0 : g == 1 ? w1 : g == 2 ? w2 : w3;
  int k0 = tk * 64, j0 = tj * 64;
  int ty = threadIdx.x >> 6, tx = threadIdx.x & 63;
#pragma unroll
  for (int r = 0; r < 16; ++r) {
    int k = k0 + ty * 16 + r;
    ls[tx][ty * 16 + r] = f2bf(W[k * 1024 + j0 + tx]);  // ls[j_local][k_local]
  }
  __syncthreads();
#pragma unroll
  for (int r = 0; r < 16; ++r) {
    int jl = ty * 16 + r;
    dst[(size_t)(g * 1024 + j0 + jl) * 1024 + k0 + tx] = ls[jl][tx];
  }
}

__global__ __launch_bounds__(256) void conv_bias_kernel(
    const float* __restrict__ b0, const float* __restrict__ b1,
    const float* __restrict__ b2, const float* __restrict__ b3,
    float* __restrict__ dst) {
  int i = blockIdx.x * 256 + threadIdx.x;  // 0..4095
  const float* s = (i >> 10) == 0 ? b0 : (i >> 10) == 1 ? b1 : (i >> 10) == 2 ? b2 : b3;
  dst[i] = s[i & 1023];
}

__global__ __launch_bounds__(256) void conv_x_kernel(
    const float4* __restrict__ src, unsigned long long* __restrict__ dst, int n4) {
  int i = blockIdx.x * 256 + threadIdx.x;
  if (i < n4) {
    float4 v = src[i];
    dst[i] = (unsigned long long)f2bf(v.x) |
             ((unsigned long long)f2bf(v.y) << 16) |
             ((unsigned long long)f2bf(v.z) << 32) |
             ((unsigned long long)f2bf(v.w) << 48);
  }
}

// ---------------- input-projection GEMM ----------------
// 256x256 tile, BK=32, 32 K-steps, 512 thr / 8 waves (2m x 4n), acc[8][4].
// Single-barrier 3-buffer counted-vmcnt pipeline (the verified step-kernel
// sync template). LDS 96KB linear. Epilogue: TWO 128-col passes through the
// [256][136] LDS bounce (round-7 bug: single pass only covered cols 0..127
// and corrupted lsC rows -> absmax 1.6; now each half is written by its
// owning waves, then streamed as 16B lines).
// XCD map: XCD x owns bn in {2x,2x+1} -> 1MB B-panels L2-resident.
__global__ __launch_bounds__(512, 2) void xproj_gemm_kernel(
    const unsigned short* __restrict__ A,   // [Mc][1024]
    const unsigned short* __restrict__ Bt,  // [4096][1024]
    unsigned short* __restrict__ C,         // [Mc][4096]
    int Mc) {
  __shared__ __align__(16) unsigned short smem[3][2][256 * 32];  // 96 KB
  int xcd = blockIdx.x & 7;               // HW round-robin block->XCD
  int i5 = blockIdx.x >> 3;
  int bn = xcd * 2 + (i5 & 1);            // 2 B-panels per XCD (1MB, L2)
  int bm = i5 >> 1;
  int m0 = bm * 256, n0 = bn * 256;
  int tid = threadIdx.x, w = tid >> 6, lane = tid & 63;
  int wm = w >> 2, wn = w & 3;
  int l15 = lane & 15, l4 = lane >> 4;

  f32x4 acc[8][4];
#pragma unroll
  for (int i = 0; i < 8; ++i)
#pragma unroll
    for (int j = 0; j < 4; ++j) acc[i][j] = (f32x4)0.f;

  auto stage = [&](int buf, int kk) {     // 4 gload16/thread, fully linear
#pragma unroll
    for (int u = 0; u < 2; ++u) {
      int cid = u * 512 + tid;
      int r = cid >> 2, kc = (cid & 3) * 8;     // r: 0..255
      gload16(&A[(size_t)(m0 + r) * 1024 + kk + kc],
              &smem[buf][0][(u * 512 + w * 64) * 8]);
    }
#pragma unroll
    for (int u = 0; u < 2; ++u) {
      int cid = u * 512 + tid;
      int r = cid >> 2, kc = (cid & 3) * 8;
      gload16(&Bt[(size_t)(n0 + r) * 1024 + kk + kc],
              &smem[buf][1][(u * 512 + w * 64) * 8]);
    }
  };
  auto compute = [&](int buf) {
    bf16x8 af[8], bfr[4];
#pragma unroll
    for (int mf = 0; mf < 8; ++mf)
      af[mf] = *(const bf16x8*)&smem[buf][0][(wm * 128 + mf * 16 + l15) * 32 + l4 * 8];
#pragma unroll
    for (int nf = 0; nf < 4; ++nf)
      bfr[nf] = *(const bf16x8*)&smem[buf][1][(wn * 64 + nf * 16 + l15) * 32 + l4 * 8];
    __builtin_amdgcn_s_setprio(1);
#pragma unroll
    for (int mf = 0; mf < 8; ++mf)
#pragma unroll
      for (int nf = 0; nf < 4; ++nf)
        acc[mf][nf] = __builtin_amdgcn_mfma_f32_16x16x32_bf16(
            af[mf], bfr[nf], acc[mf][nf], 0, 0, 0);
    __builtin_amdgcn_s_setprio(0);
  };

  // prologue: 2 stages in flight (8 loads)
  stage(0, 0);
  stage(1, 32);
#pragma unroll
  for (int it = 0; it < 32; ++it) {
    // my stage(it) landed (leaves stage(it+1)'s 4 loads in flight)
    if (it < 31) asm volatile("s_waitcnt vmcnt(4)" ::: "memory");
    else         asm volatile("s_waitcnt vmcnt(0)" ::: "memory");
    __builtin_amdgcn_sched_barrier(0);
    __builtin_amdgcn_s_barrier();     // stage(it) landed + prev reads retired
    __builtin_amdgcn_sched_barrier(0);
    if (it + 2 < 32) stage((it + 2) % 3, (it + 2) * 32);  // overwrite safe now
    compute(it % 3);
    asm volatile("s_waitcnt lgkmcnt(0)" ::: "memory");    // my ds_reads done
    __builtin_amdgcn_sched_barrier(0);
  }

  // ---- epilogue: acc -> LDS (bf16) -> coalesced 16B stores, 2 col-halves --
  unsigned short* lsC = &smem[0][0][0];   // [256][136] = 69632 B (fits 96KB)
#pragma unroll
  for (int h = 0; h < 2; ++h) {
    __syncthreads();                      // prev phase (K-loop / pass-0 reads)
    if ((wn >> 1) == h) {                 // waves owning cols [h*128, h*128+128)
#pragma unroll
      for (int mf = 0; mf < 8; ++mf)
#pragma unroll
        for (int nf = 0; nf < 4; ++nf)
#pragma unroll
          for (int r = 0; r < 4; ++r) {
            int row = wm * 128 + mf * 16 + l4 * 4 + r;
            int col = (wn & 1) * 64 + nf * 16 + l15;
            lsC[row * 136 + col] = f2bf(acc[mf][nf][r]);
          }
    }
    __syncthreads();
#pragma unroll
    for (int u = 0; u < 8; ++u) {
      int chunk = u * 512 + tid;      // 0..4095 : 256 rows x 16 chunks of 16B
      int row = chunk >> 4, c8 = chunk & 15;
      bf16x8 v = *(const bf16x8*)&lsC[row * 136 + c8 * 8];
      *(bf16x8*)&C[(size_t)(m0 + row) * 4096 + n0 + h * 128 + c8 * 8] = v;
    }
  }
}

// ---------------- fused LSTM step (per-step launch) ----------------
// Tile (32 batch x 64 hidden x 4 gates), 256 threads / 4 waves, 72KB LDS
// -> grid 512 = 2 blocks/CU (decorrelated barrier groups per SIMD).
// A-rows [b_half][gate][b_lo]; XCD map: XCD x owns bb in {4x..4x+3} (1MB Wh)
// + all bj (2MB hT) -> L2-resident staging. Single-barrier 3-buffer
// pipeline, counted vmcnt (6-load stages). UNCHANGED from round 6.
__global__ __launch_bounds__(256) void lstm_step_kernel(
    const unsigned short* __restrict__ Wh,   // [4096][1024]
    const unsigned short* __restrict__ hT,   // [1024][1024]  hT[j][k]=h[k][j]
    const unsigned short* __restrict__ Xp,   // [1024][4096]  this step's x-proj
    const float* __restrict__ bias,          // [4096]
    float* __restrict__ cst,                 // [1024*1024] fp32 cell state
    float* __restrict__ out_h,               // d_out + t*1M
    float* __restrict__ out_ht,              // d_out + T*1M
    float* __restrict__ out_ct,              // d_out + T*1M + 1M
    unsigned short* __restrict__ hT_next,    // other hT buffer
    int isLast) {
  __shared__ unsigned short lsA[3][128 * 64];  // [b_half][gate][b_lo] x 64k
  __shared__ unsigned short lsB[3][64 * 64];
  int bx = blockIdx.x;
  int xcd = bx & 7, idx = bx >> 3;             // idx in [0,64)
  int bb = xcd * 4 + (idx & 3);                // [0,32): XCD-local Wh slice
  int bj = idx >> 2;                           // [0,16)
  int b0 = bb * 32, j0 = bj * 64;
  int tid = threadIdx.x, w = tid >> 6, lane = tid & 63;
  int wm = w >> 1, wn = w & 1;
  int l15 = lane & 15, l4 = lane >> 4;
  int bbase = b0 + wm * 16 + l4 * 4;

  // ---- prefetch epilogue operands (issued first -> oldest in vmcnt FIFO;
  //      it0's vmcnt(6) drains them along with stage(0)) ----
  float bias_pre[4][2];
  float c_pre[2][4];
  unsigned short xp_pre[4][2][4];
#pragma unroll
  for (int n = 0; n < 2; ++n) {
    int j = j0 + wn * 32 + n * 16 + l15;
#pragma unroll
    for (int g = 0; g < 4; ++g) bias_pre[g][n] = bias[g * 1024 + j];
#pragma unroll
    for (int r = 0; r < 4; ++r) {
      c_pre[n][r] = cst[(size_t)(bbase + r) * 1024 + j];
#pragma unroll
      for (int g = 0; g < 4; ++g)
        xp_pre[g][n][r] = Xp[(size_t)(bbase + r) * 4096 + g * 1024 + j];
    }
  }

  f32x4 acc[4][2];
#pragma unroll
  for (int g = 0; g < 4; ++g)
#pragma unroll
    for (int n = 0; n < 2; ++n) acc[g][n] = (f32x4)0.f;

  auto stage = [&](int buf, int kk) {          // 6 gload16 per thread
#pragma unroll
    for (int ld = 0; ld < 4; ++ld) {
      int cid = ld * 256 + tid;
      int r = cid >> 3, kc = (cid & 7) * 8;    // r: 0..127 local A-row
      int sk = kk + (kc ^ ((r & 7) << 3));
      // local row r = b_half*64 + g*16 + b_lo  ->  Wh row g*1024 + b0 + b
      int grow = ((r >> 4) & 3) * 1024 + b0 + (r >> 6) * 16 + (r & 15);
      gload16(&Wh[(size_t)grow * 1024 + sk], &lsA[buf][(ld * 256 + w * 64) * 8]);
    }
#pragma unroll
    for (int u = 0; u < 2; ++u) {
      int cid = u * 256 + tid;
      int r = cid >> 3, kc = (cid & 7) * 8;    // r: 0..63
      int sk = kk + (kc ^ ((r & 7) << 3));
      gload16(&hT[(size_t)(j0 + r) * 1024 + sk], &lsB[buf][(u * 256 + w * 64) * 8]);
    }
  };
  auto compute = [&](int buf) {
    bf16x8 af[4][2], bfr[2][2];
#pragma unroll
    for (int g = 0; g < 4; ++g)
#pragma unroll
      for (int kss = 0; kss < 2; ++kss) {
        int e = (wm * 64 + g * 16 + l15) * 64 + kss * 32 + l4 * 8;
        af[g][kss] = *(const bf16x8*)&lsA[buf][swz(e)];
      }
#pragma unroll
    for (int n = 0; n < 2; ++n)
#pragma unroll
      for (int kss = 0; kss < 2; ++kss) {
        int e = (wn * 32 + n * 16 + l15) * 64 + kss * 32 + l4 * 8;
        bfr[n][kss] = *(const bf16x8*)&lsB[buf][swz(e)];
      }
    __builtin_amdgcn_s_setprio(1);
#pragma unroll
    for (int g = 0; g < 4; ++g)
#pragma unroll
      for (int n = 0; n < 2; ++n)
#pragma unroll
        for (int kss = 0; kss < 2; ++kss)
          acc[g][n] = __builtin_amdgcn_mfma_f32_16x16x32_bf16(
              af[g][kss], bfr[n][kss], acc[g][n], 0, 0, 0);
    __builtin_amdgcn_s_setprio(0);
  };

  // prologue: 2 stages in flight (48 prefetch + 12 staging = 60 <= 63)
  stage(0, 0);
  stage(1, 64);
#pragma unroll
  for (int it = 0; it < 16; ++it) {
    // my stage(it) landed (leaves stage(it+1)'s 6 loads in flight)
    if (it < 15) asm volatile("s_waitcnt vmcnt(6)" ::: "memory");
    else         asm volatile("s_waitcnt vmcnt(0)" ::: "memory");
    __builtin_amdgcn_sched_barrier(0);
    __builtin_amdgcn_s_barrier();     // stage(it) landed + prev reads retired
    __builtin_amdgcn_sched_barrier(0);
    if (it + 2 < 16) stage((it + 2) % 3, (it + 2) * 64);  // overwrite safe now
    compute(it % 3);
    asm volatile("s_waitcnt lgkmcnt(0)" ::: "memory");    // my ds_reads done
    __builtin_amdgcn_sched_barrier(0);
  }

  // epilogue: gates + cell/hidden update (operands already in registers)
#pragma unroll
  for (int n = 0; n < 2; ++n) {
    int j = j0 + wn * 32 + n * 16 + l15;
    float hn[4], cn[4];
#pragma unroll
    for (int r = 0; r < 4; ++r) {
      int b = bbase + r;
      float pi = acc[0][n][r] + bf2f(xp_pre[0][n][r]) + bias_pre[0][n];
      float pf = acc[1][n][r] + bf2f(xp_pre[1][n][r]) + bias_pre[1][n];
      float pg = acc[2][n][r] + bf2f(xp_pre[2][n][r]) + bias_pre[2][n];
      float po = acc[3][n][r] + bf2f(xp_pre[3][n][r]) + bias_pre[3][n];
      float ig = sigm(pi), fg = sigm(pf), gg = tanh_f(pg), og = sigm(po);
      float c_new = fg * c_pre[n][r] + ig * gg;
      cst[(size_t)b * 1024 + j] = c_new;
      cn[r] = c_new;
      hn[r] = og * tanh_f(c_new);
      out_h[(size_t)b * 1024 + j] = hn[r];
    }
    unsigned long long hp = (unsigned long long)f2bf(hn[0]) |
                            ((unsigned long long)f2bf(hn[1]) << 16) |
                            ((unsigned long long)f2bf(hn[2]) << 32) |
                            ((unsigned long long)f2bf(hn[3]) << 48);
    *(unsigned long long*)&hT_next[(size_t)j * 1024 + bbase] = hp;
    if (isLast) {
#pragma unroll
      for (int r = 0; r < 4; ++r) {
        int b = bbase + r;
        out_ht[(size_t)b * 1024 + j] = hn[r];
        out_ct[(size_t)b * 1024 + j] = cn[r];
      }
    }
  }
}

// ---------------- host ----------------
extern "C" void kernel_launch(void* const* d_in, const int* in_sizes, int n_in,
                              void* d_out, int out_size, void* d_ws, size_t ws_size,
                              hipStream_t stream) {
  const float* X   = (const float*)d_in[0];
  const float* Wii = (const float*)d_in[1];
  const float* Whi = (const float*)d_in[2];
  const float* bi  = (const float*)d_in[3];
  const float* Wif = (const float*)d_in[4];
  const float* Whf = (const float*)d_in[5];
  const float* bfv = (const float*)d_in[6];
  const float* Wig = (const float*)d_in[7];
  const float* Whg = (const float*)d_in[8];
  const float* bg  = (const float*)d_in[9];
  const float* Wio = (const float*)d_in[10];
  const float* Who = (const float*)d_in[11];
  const float* bo  = (const float*)d_in[12];
  float* out = (float*)d_out;

  char* wsp = (char*)d_ws;
  size_t off = 0;
  auto walloc = [&](size_t b) -> void* {
    void* p = wsp + off;
    off += (b + 255) & ~(size_t)255;
    return p;
  };
  unsigned short* WiT = (unsigned short*)walloc(4096ull * 1024 * 2);
  unsigned short* Wh  = (unsigned short*)walloc(4096ull * 1024 * 2);
  float* bias = (float*)walloc(4096 * 4);
  unsigned short* hT0 = (unsigned short*)walloc(1024ull * 1024 * 2);
  unsigned short* hT1 = (unsigned short*)walloc(1024ull * 1024 * 2);
  float* cbuf = (float*)walloc(1024ull * 1024 * 4);
  size_t fixed = off;

  long long avail = (long long)ws_size - (long long)fixed - (1ll << 20);
  int Tc = (int)(avail / (10ll << 20));   // 2MB Xbf + 8MB Xproj per step
  if (Tc < 1) Tc = 1;
  if (Tc > 128) Tc = 128;
  unsigned short* Xbf = (unsigned short*)walloc((size_t)Tc * 1024 * 1024 * 2);
  unsigned short* Xp  = (unsigned short*)walloc((size_t)Tc * 1024 * 4096 * 2);

  conv_wh_kernel<<<4096, 256, 0, stream>>>((const float4*)Whi, (const float4*)Whf,
                                           (const float4*)Whg, (const float4*)Who,
                                           (unsigned long long*)Wh);
  conv_wiT_kernel<<<1024, 256, 0, stream>>>(Wii, Wif, Wig, Wio, WiT);
  conv_bias_kernel<<<16, 256, 0, stream>>>(bi, bfv, bg, bo, bias);
  hipMemsetAsync(hT0, 0, 1024ull * 1024 * 2, stream);
  hipMemsetAsync(cbuf, 0, 1024ull * 1024 * 4, stream);

  for (int t0 = 0; t0 < 128; t0 += Tc) {
    int tc = (128 - t0 < Tc) ? (128 - t0) : Tc;
    int n4 = tc * 262144;
    conv_x_kernel<<<n4 / 256, 256, 0, stream>>>(
        (const float4*)(X + (size_t)t0 * 1048576),
        (unsigned long long*)Xbf, n4);
    xproj_gemm_kernel<<<tc * 64, 512, 0, stream>>>(Xbf, WiT, Xp, tc * 1024);
    for (int i = 0; i < tc; ++i) {
      int t = t0 + i;
      lstm_step_kernel<<<512, 256, 0, stream>>>(
          Wh, (t & 1) ? hT1 : hT0,
          Xp + (size_t)i * 1024 * 4096,
          bias, cbuf,
          out + (size_t)t * 1048576,
          out + 134217728ull,
          out + 135266304ull,
          (t & 1) ? hT0 : hT1,
          (t == 127) ? 1 : 0);
    }
  }
}

// Round 9
// 3564.496 us; speedup vs baseline: 1.0096x; 1.0096x over previous
//
#include <hip/hip_runtime.h>
#include <cstdint>

typedef __attribute__((ext_vector_type(8))) short bf16x8;
typedef __attribute__((ext_vector_type(4))) float f32x4;

#define AS1 __attribute__((address_space(1)))
#define AS3 __attribute__((address_space(3)))

__device__ __forceinline__ unsigned short f2bf(float f) {
  unsigned int u = __builtin_bit_cast(unsigned int, f);
  return (unsigned short)((u + 0x7fffu + ((u >> 16) & 1u)) >> 16);
}
__device__ __forceinline__ float bf2f(unsigned short h) {
  unsigned int u = ((unsigned int)h) << 16;
  return __builtin_bit_cast(float, u);
}
__device__ __forceinline__ float sigm(float x) { return 1.f / (1.f + __expf(-x)); }
__device__ __forceinline__ float tanh_f(float x) {
  float e = __expf(2.f * x);          // inf-safe: e=inf -> 1, e=0 -> -1
  return 1.f - 2.f / (e + 1.f);
}
__device__ __forceinline__ void gload16(const void* g, void* l) {
  __builtin_amdgcn_global_load_lds((const AS1 unsigned int*)g, (AS3 unsigned int*)l, 16, 0, 0);
}
// XOR-swizzle for [rows][64]-bf16 tiles (step kernel; 8 slots of 16B/row).
__device__ __forceinline__ int swz(int e) { return e ^ (((e >> 6) & 7) << 3); }
// XOR-swizzle for [rows][32]-bf16 tiles (xproj; 4 slots of 16B per 64B row).
// slot' = slot ^ ((row>>1)&3): even rows cover banks 0-15, odd rows 16-31,
// (l15,l4)->slot map bijective over the wave's 1KB window -> every bank
// exactly 8 dwords (minimal; round-8 linear layout was ~8-way, 104.9M cyc).
__device__ __forceinline__ int sl32(int row, int slot) {
  return row * 32 + ((slot ^ ((row >> 1) & 3)) << 3);
}

// ---------------- setup / conversion kernels ----------------

__global__ __launch_bounds__(256) void conv_wh_kernel(
    const float4* __restrict__ w0, const float4* __restrict__ w1,
    const float4* __restrict__ w2, const float4* __restrict__ w3,
    unsigned long long* __restrict__ dst) {
  int i = blockIdx.x * 256 + threadIdx.x;           // 0 .. 1M-1 (float4 units)
  int g = i >> 18;                                  // 262144 float4 per matrix
  const float4* s = g == 0 ? w0 : g == 1 ? w1 : g == 2 ? w2 : w3;
  float4 v = s[i & 0x3FFFF];
  unsigned long long p = (unsigned long long)f2bf(v.x) |
                         ((unsigned long long)f2bf(v.y) << 16) |
                         ((unsigned long long)f2bf(v.z) << 32) |
                         ((unsigned long long)f2bf(v.w) << 48);
  dst[i] = p;
}

__global__ __launch_bounds__(256) void conv_wiT_kernel(
    const float* __restrict__ w0, const float* __restrict__ w1,
    const float* __restrict__ w2, const float* __restrict__ w3,
    unsigned short* __restrict__ dst) {
  __shared__ unsigned short ls[64][72];
  int bid = blockIdx.x;                 // 0..1023 : 4 gates x 16x16 tiles
  int g = bid >> 8;
  int t2 = bid & 255;
  int tj = t2 & 15, tk = t2 >> 4;
  const float* W = g == 0 ? w0 : g == 1 ? w1 : g == 2 ? w2 : w3;
  int k0 = tk * 64, j0 = tj * 64;
  int ty = threadIdx.x >> 6, tx = threadIdx.x & 63;
#pragma unroll
  for (int r = 0; r < 16; ++r) {
    int k = k0 + ty * 16 + r;
    ls[tx][ty * 16 + r] = f2bf(W[k * 1024 + j0 + tx]);  // ls[j_local][k_local]
  }
  __syncthreads();
#pragma unroll
  for (int r = 0; r < 16; ++r) {
    int jl = ty * 16 + r;
    dst[(size_t)(g * 1024 + j0 + jl) * 1024 + k0 + tx] = ls[jl][tx];
  }
}

__global__ __launch_bounds__(256) void conv_bias_kernel(
    const float* __restrict__ b0, const float* __restrict__ b1,
    const float* __restrict__ b2, const float* __restrict__ b3,
    float* __restrict__ dst) {
  int i = blockIdx.x * 256 + threadIdx.x;  // 0..4095
  const float* s = (i >> 10) == 0 ? b0 : (i >> 10) == 1 ? b1 : (i >> 10) == 2 ? b2 : b3;
  dst[i] = s[i & 1023];
}

__global__ __launch_bounds__(256) void conv_x_kernel(
    const float4* __restrict__ src, unsigned long long* __restrict__ dst, int n4) {
  int i = blockIdx.x * 256 + threadIdx.x;
  if (i < n4) {
    float4 v = src[i];
    dst[i] = (unsigned long long)f2bf(v.x) |
             ((unsigned long long)f2bf(v.y) << 16) |
             ((unsigned long long)f2bf(v.z) << 32) |
             ((unsigned long long)f2bf(v.w) << 48);
  }
}

// ---------------- input-projection GEMM ----------------
// 256x256 tile, BK=32, 32 K-steps, 512 thr / 8 waves (2m x 4n), acc[8][4].
// Single-barrier 3-buffer counted-vmcnt pipeline. LDS 96KB, sl32-swizzled
// (pre-swizzled global source + swizzled fragment read, linear LDS dest --
// rule #21). Epilogue: two 128-col passes through [256][136] LDS bounce.
// XCD map: XCD x owns bn in {2x,2x+1} -> 1MB B-panels L2-resident.
__global__ __launch_bounds__(512, 2) void xproj_gemm_kernel(
    const unsigned short* __restrict__ A,   // [Mc][1024]
    const unsigned short* __restrict__ Bt,  // [4096][1024]
    unsigned short* __restrict__ C,         // [Mc][4096]
    int Mc) {
  __shared__ __align__(16) unsigned short smem[3][2][256 * 32];  // 96 KB
  int xcd = blockIdx.x & 7;               // HW round-robin block->XCD
  int i5 = blockIdx.x >> 3;
  int bn = xcd * 2 + (i5 & 1);            // 2 B-panels per XCD (1MB, L2)
  int bm = i5 >> 1;
  int m0 = bm * 256, n0 = bn * 256;
  int tid = threadIdx.x, w = tid >> 6, lane = tid & 63;
  int wm = w >> 2, wn = w & 3;
  int l15 = lane & 15, l4 = lane >> 4;

  f32x4 acc[8][4];
#pragma unroll
  for (int i = 0; i < 8; ++i)
#pragma unroll
    for (int j = 0; j < 4; ++j) acc[i][j] = (f32x4)0.f;

  auto stage = [&](int buf, int kk) {     // 4 gload16/thread, linear LDS dest
#pragma unroll
    for (int u = 0; u < 2; ++u) {
      int cid = u * 512 + tid;
      int r = cid >> 2, s = cid & 3;            // r: 0..255, slot: 0..3
      int sk = kk + ((s ^ ((r >> 1) & 3)) << 3);  // inverse-swizzled source
      gload16(&A[(size_t)(m0 + r) * 1024 + sk],
              &smem[buf][0][(u * 512 + w * 64) * 8]);
    }
#pragma unroll
    for (int u = 0; u < 2; ++u) {
      int cid = u * 512 + tid;
      int r = cid >> 2, s = cid & 3;
      int sk = kk + ((s ^ ((r >> 1) & 3)) << 3);
      gload16(&Bt[(size_t)(n0 + r) * 1024 + sk],
              &smem[buf][1][(u * 512 + w * 64) * 8]);
    }
  };
  auto compute = [&](int buf) {
    bf16x8 af[8], bfr[4];
#pragma unroll
    for (int mf = 0; mf < 8; ++mf)
      af[mf] = *(const bf16x8*)&smem[buf][0][sl32(wm * 128 + mf * 16 + l15, l4)];
#pragma unroll
    for (int nf = 0; nf < 4; ++nf)
      bfr[nf] = *(const bf16x8*)&smem[buf][1][sl32(wn * 64 + nf * 16 + l15, l4)];
    __builtin_amdgcn_s_setprio(1);
#pragma unroll
    for (int mf = 0; mf < 8; ++mf)
#pragma unroll
      for (int nf = 0; nf < 4; ++nf)
        acc[mf][nf] = __builtin_amdgcn_mfma_f32_16x16x32_bf16(
            af[mf], bfr[nf], acc[mf][nf], 0, 0, 0);
    __builtin_amdgcn_s_setprio(0);
  };

  // prologue: 2 stages in flight (8 loads)
  stage(0, 0);
  stage(1, 32);
#pragma unroll
  for (int it = 0; it < 32; ++it) {
    // my stage(it) landed (leaves stage(it+1)'s 4 loads in flight)
    if (it < 31) asm volatile("s_waitcnt vmcnt(4)" ::: "memory");
    else         asm volatile("s_waitcnt vmcnt(0)" ::: "memory");
    __builtin_amdgcn_sched_barrier(0);
    __builtin_amdgcn_s_barrier();     // stage(it) landed + prev reads retired
    __builtin_amdgcn_sched_barrier(0);
    if (it + 2 < 32) stage((it + 2) % 3, (it + 2) * 32);  // overwrite safe now
    compute(it % 3);
    asm volatile("s_waitcnt lgkmcnt(0)" ::: "memory");    // my ds_reads done
    __builtin_amdgcn_sched_barrier(0);
  }

  // ---- epilogue: acc -> LDS (bf16) -> coalesced 16B stores, 2 col-halves --
  unsigned short* lsC = &smem[0][0][0];   // [256][136] = 69632 B (fits 96KB)
#pragma unroll
  for (int h = 0; h < 2; ++h) {
    __syncthreads();                      // prev phase (K-loop / pass-0 reads)
    if ((wn >> 1) == h) {                 // waves owning cols [h*128, h*128+128)
#pragma unroll
      for (int mf = 0; mf < 8; ++mf)
#pragma unroll
        for (int nf = 0; nf < 4; ++nf)
#pragma unroll
          for (int r = 0; r < 4; ++r) {
            int row = wm * 128 + mf * 16 + l4 * 4 + r;
            int col = (wn & 1) * 64 + nf * 16 + l15;
            lsC[row * 136 + col] = f2bf(acc[mf][nf][r]);
          }
    }
    __syncthreads();
#pragma unroll
    for (int u = 0; u < 8; ++u) {
      int chunk = u * 512 + tid;      // 0..4095 : 256 rows x 16 chunks of 16B
      int row = chunk >> 4, c8 = chunk & 15;
      bf16x8 v = *(const bf16x8*)&lsC[row * 136 + c8 * 8];
      *(bf16x8*)&C[(size_t)(m0 + row) * 4096 + n0 + h * 128 + c8 * 8] = v;
    }
  }
}

// ---------------- fused LSTM step (per-step launch) ----------------
// Tile (32 batch x 64 hidden x 4 gates), 256 threads / 4 waves, 72KB LDS
// -> grid 512 = 2 blocks/CU (decorrelated barrier groups per SIMD).
// A-rows [b_half][gate][b_lo]; XCD map: XCD x owns bb in {4x..4x+3} (1MB Wh)
// + all bj (2MB hT) -> L2-resident staging. Single-barrier 3-buffer
// pipeline, counted vmcnt (6-load stages). UNCHANGED from round 6.
__global__ __launch_bounds__(256) void lstm_step_kernel(
    const unsigned short* __restrict__ Wh,   // [4096][1024]
    const unsigned short* __restrict__ hT,   // [1024][1024]  hT[j][k]=h[k][j]
    const unsigned short* __restrict__ Xp,   // [1024][4096]  this step's x-proj
    const float* __restrict__ bias,          // [4096]
    float* __restrict__ cst,                 // [1024*1024] fp32 cell state
    float* __restrict__ out_h,               // d_out + t*1M
    float* __restrict__ out_ht,              // d_out + T*1M
    float* __restrict__ out_ct,              // d_out + T*1M + 1M
    unsigned short* __restrict__ hT_next,    // other hT buffer
    int isLast) {
  __shared__ unsigned short lsA[3][128 * 64];  // [b_half][gate][b_lo] x 64k
  __shared__ unsigned short lsB[3][64 * 64];
  int bx = blockIdx.x;
  int xcd = bx & 7, idx = bx >> 3;             // idx in [0,64)
  int bb = xcd * 4 + (idx & 3);                // [0,32): XCD-local Wh slice
  int bj = idx >> 2;                           // [0,16)
  int b0 = bb * 32, j0 = bj * 64;
  int tid = threadIdx.x, w = tid >> 6, lane = tid & 63;
  int wm = w >> 1, wn = w & 1;
  int l15 = lane & 15, l4 = lane >> 4;
  int bbase = b0 + wm * 16 + l4 * 4;

  // ---- prefetch epilogue operands (issued first -> oldest in vmcnt FIFO;
  //      it0's vmcnt(6) drains them along with stage(0)) ----
  float bias_pre[4][2];
  float c_pre[2][4];
  unsigned short xp_pre[4][2][4];
#pragma unroll
  for (int n = 0; n < 2; ++n) {
    int j = j0 + wn * 32 + n * 16 + l15;
#pragma unroll
    for (int g = 0; g < 4; ++g) bias_pre[g][n] = bias[g * 1024 + j];
#pragma unroll
    for (int r = 0; r < 4; ++r) {
      c_pre[n][r] = cst[(size_t)(bbase + r) * 1024 + j];
#pragma unroll
      for (int g = 0; g < 4; ++g)
        xp_pre[g][n][r] = Xp[(size_t)(bbase + r) * 4096 + g * 1024 + j];
    }
  }

  f32x4 acc[4][2];
#pragma unroll
  for (int g = 0; g < 4; ++g)
#pragma unroll
    for (int n = 0; n < 2; ++n) acc[g][n] = (f32x4)0.f;

  auto stage = [&](int buf, int kk) {          // 6 gload16 per thread
#pragma unroll
    for (int ld = 0; ld < 4; ++ld) {
      int cid = ld * 256 + tid;
      int r = cid >> 3, kc = (cid & 7) * 8;    // r: 0..127 local A-row
      int sk = kk + (kc ^ ((r & 7) << 3));
      // local row r = b_half*64 + g*16 + b_lo  ->  Wh row g*1024 + b0 + b
      int grow = ((r >> 4) & 3) * 1024 + b0 + (r >> 6) * 16 + (r & 15);
      gload16(&Wh[(size_t)grow * 1024 + sk], &lsA[buf][(ld * 256 + w * 64) * 8]);
    }
#pragma unroll
    for (int u = 0; u < 2; ++u) {
      int cid = u * 256 + tid;
      int r = cid >> 3, kc = (cid & 7) * 8;    // r: 0..63
      int sk = kk + (kc ^ ((r & 7) << 3));
      gload16(&hT[(size_t)(j0 + r) * 1024 + sk], &lsB[buf][(u * 256 + w * 64) * 8]);
    }
  };
  auto compute = [&](int buf) {
    bf16x8 af[4][2], bfr[2][2];
#pragma unroll
    for (int g = 0; g < 4; ++g)
#pragma unroll
      for (int kss = 0; kss < 2; ++kss) {
        int e = (wm * 64 + g * 16 + l15) * 64 + kss * 32 + l4 * 8;
        af[g][kss] = *(const bf16x8*)&lsA[buf][swz(e)];
      }
#pragma unroll
    for (int n = 0; n < 2; ++n)
#pragma unroll
      for (int kss = 0; kss < 2; ++kss) {
        int e = (wn * 32 + n * 16 + l15) * 64 + kss * 32 + l4 * 8;
        bfr[n][kss] = *(const bf16x8*)&lsB[buf][swz(e)];
      }
    __builtin_amdgcn_s_setprio(1);
#pragma unroll
    for (int g = 0; g < 4; ++g)
#pragma unroll
      for (int n = 0; n < 2; ++n)
#pragma unroll
        for (int kss = 0; kss < 2; ++kss)
          acc[g][n] = __builtin_amdgcn_mfma_f32_16x16x32_bf16(
              af[g][kss], bfr[n][kss], acc[g][n], 0, 0, 0);
    __builtin_amdgcn_s_setprio(0);
  };

  // prologue: 2 stages in flight (48 prefetch + 12 staging = 60 <= 63)
  stage(0, 0);
  stage(1, 64);
#pragma unroll
  for (int it = 0; it < 16; ++it) {
    // my stage(it) landed (leaves stage(it+1)'s 6 loads in flight)
    if (it < 15) asm volatile("s_waitcnt vmcnt(6)" ::: "memory");
    else         asm volatile("s_waitcnt vmcnt(0)" ::: "memory");
    __builtin_amdgcn_sched_barrier(0);
    __builtin_amdgcn_s_barrier();     // stage(it) landed + prev reads retired
    __builtin_amdgcn_sched_barrier(0);
    if (it + 2 < 16) stage((it + 2) % 3, (it + 2) * 64);  // overwrite safe now
    compute(it % 3);
    asm volatile("s_waitcnt lgkmcnt(0)" ::: "memory");    // my ds_reads done
    __builtin_amdgcn_sched_barrier(0);
  }

  // epilogue: gates + cell/hidden update (operands already in registers)
#pragma unroll
  for (int n = 0; n < 2; ++n) {
    int j = j0 + wn * 32 + n * 16 + l15;
    float hn[4], cn[4];
#pragma unroll
    for (int r = 0; r < 4; ++r) {
      int b = bbase + r;
      float pi = acc[0][n][r] + bf2f(xp_pre[0][n][r]) + bias_pre[0][n];
      float pf = acc[1][n][r] + bf2f(xp_pre[1][n][r]) + bias_pre[1][n];
      float pg = acc[2][n][r] + bf2f(xp_pre[2][n][r]) + bias_pre[2][n];
      float po = acc[3][n][r] + bf2f(xp_pre[3][n][r]) + bias_pre[3][n];
      float ig = sigm(pi), fg = sigm(pf), gg = tanh_f(pg), og = sigm(po);
      float c_new = fg * c_pre[n][r] + ig * gg;
      cst[(size_t)b * 1024 + j] = c_new;
      cn[r] = c_new;
      hn[r] = og * tanh_f(c_new);
      out_h[(size_t)b * 1024 + j] = hn[r];
    }
    unsigned long long hp = (unsigned long long)f2bf(hn[0]) |
                            ((unsigned long long)f2bf(hn[1]) << 16) |
                            ((unsigned long long)f2bf(hn[2]) << 32) |
                            ((unsigned long long)f2bf(hn[3]) << 48);
    *(unsigned long long*)&hT_next[(size_t)j * 1024 + bbase] = hp;
    if (isLast) {
#pragma unroll
      for (int r = 0; r < 4; ++r) {
        int b = bbase + r;
        out_ht[(size_t)b * 1024 + j] = hn[r];
        out_ct[(size_t)b * 1024 + j] = cn[r];
      }
    }
  }
}

// ---------------- host ----------------
extern "C" void kernel_launch(void* const* d_in, const int* in_sizes, int n_in,
                              void* d_out, int out_size, void* d_ws, size_t ws_size,
                              hipStream_t stream) {
  const float* X   = (const float*)d_in[0];
  const float* Wii = (const float*)d_in[1];
  const float* Whi = (const float*)d_in[2];
  const float* bi  = (const float*)d_in[3];
  const float* Wif = (const float*)d_in[4];
  const float* Whf = (const float*)d_in[5];
  const float* bfv = (const float*)d_in[6];
  const float* Wig = (const float*)d_in[7];
  const float* Whg = (const float*)d_in[8];
  const float* bg  = (const float*)d_in[9];
  const float* Wio = (const float*)d_in[10];
  const float* Who = (const float*)d_in[11];
  const float* bo  = (const float*)d_in[12];
  float* out = (float*)d_out;

  char* wsp = (char*)d_ws;
  size_t off = 0;
  auto walloc = [&](size_t b) -> void* {
    void* p = wsp + off;
    off += (b + 255) & ~(size_t)255;
    return p;
  };
  unsigned short* WiT = (unsigned short*)walloc(4096ull * 1024 * 2);
  unsigned short* Wh  = (unsigned short*)walloc(4096ull * 1024 * 2);
  float* bias = (float*)walloc(4096 * 4);
  unsigned short* hT0 = (unsigned short*)walloc(1024ull * 1024 * 2);
  unsigned short* hT1 = (unsigned short*)walloc(1024ull * 1024 * 2);
  float* cbuf = (float*)walloc(1024ull * 1024 * 4);
  size_t fixed = off;

  long long avail = (long long)ws_size - (long long)fixed - (1ll << 20);
  int Tc = (int)(avail / (10ll << 20));   // 2MB Xbf + 8MB Xproj per step
  if (Tc < 1) Tc = 1;
  if (Tc > 128) Tc = 128;
  unsigned short* Xbf = (unsigned short*)walloc((size_t)Tc * 1024 * 1024 * 2);
  unsigned short* Xp  = (unsigned short*)walloc((size_t)Tc * 1024 * 4096 * 2);

  conv_wh_kernel<<<4096, 256, 0, stream>>>((const float4*)Whi, (const float4*)Whf,
                                           (const float4*)Whg, (const float4*)Who,
                                           (unsigned long long*)Wh);
  conv_wiT_kernel<<<1024, 256, 0, stream>>>(Wii, Wif, Wig, Wio, WiT);
  conv_bias_kernel<<<16, 256, 0, stream>>>(bi, bfv, bg, bo, bias);
  hipMemsetAsync(hT0, 0, 1024ull * 1024 * 2, stream);
  hipMemsetAsync(cbuf, 0, 1024ull * 1024 * 4, stream);

  for (int t0 = 0; t0 < 128; t0 += Tc) {
    int tc = (128 - t0 < Tc) ? (128 - t0) : Tc;
    int n4 = tc * 262144;
    conv_x_kernel<<<n4 / 256, 256, 0, stream>>>(
        (const float4*)(X + (size_t)t0 * 1048576),
        (unsigned long long*)Xbf, n4);
    xproj_gemm_kernel<<<tc * 64, 512, 0, stream>>>(Xbf, WiT, Xp, tc * 1024);
    for (int i = 0; i < tc; ++i) {
      int t = t0 + i;
      lstm_step_kernel<<<512, 256, 0, stream>>>(
          Wh, (t & 1) ? hT1 : hT0,
          Xp + (size_t)i * 1024 * 4096,
          bias, cbuf,
          out + (size_t)t * 1048576,
          out + 134217728ull,
          out + 135266304ull,
          (t & 1) ? hT0 : hT1,
          (t == 127) ? 1 : 0);
    }
  }
}

// Round 11
// 3432.058 us; speedup vs baseline: 1.0485x; 1.0386x over previous
//
#include <hip/hip_runtime.h>
#include <cstdint>

typedef __attribute__((ext_vector_type(8))) short bf16x8;
typedef __attribute__((ext_vector_type(4))) float f32x4;
typedef __attribute__((ext_vector_type(4))) unsigned int u32x4;

#define AS1 __attribute__((address_space(1)))
#define AS3 __attribute__((address_space(3)))

__device__ __forceinline__ unsigned short f2bf(float f) {
  unsigned int u = __builtin_bit_cast(unsigned int, f);
  return (unsigned short)((u + 0x7fffu + ((u >> 16) & 1u)) >> 16);
}
__device__ __forceinline__ float bf2f(unsigned short h) {
  unsigned int u = ((unsigned int)h) << 16;
  return __builtin_bit_cast(float, u);
}
__device__ __forceinline__ float sigm(float x) { return 1.f / (1.f + __expf(-x)); }
__device__ __forceinline__ float tanh_f(float x) {
  float e = __expf(2.f * x);          // inf-safe: e=inf -> 1, e=0 -> -1
  return 1.f - 2.f / (e + 1.f);
}
__device__ __forceinline__ void gload16(const void* g, void* l) {
  __builtin_amdgcn_global_load_lds((const AS1 unsigned int*)g, (AS3 unsigned int*)l, 16, 0, 0);
}
// XOR-swizzle for [rows][64]-bf16 tiles (8 slots of 16B per 128B row):
// slot' = slot ^ (row&7). Proven in the step kernel; now also xproj (BK=64).
// Staging pre-swizzles the GLOBAL source, LDS dest linear, reads swizzled
// (rule #21 both-sides).
__device__ __forceinline__ int swz(int e) { return e ^ (((e >> 6) & 7) << 3); }

// ---------------- setup / conversion kernels ----------------

__global__ __launch_bounds__(256) void conv_wh_kernel(
    const float4* __restrict__ w0, const float4* __restrict__ w1,
    const float4* __restrict__ w2, const float4* __restrict__ w3,
    unsigned long long* __restrict__ dst) {
  int i = blockIdx.x * 256 + threadIdx.x;           // 0 .. 1M-1 (float4 units)
  int g = i >> 18;                                  // 262144 float4 per matrix
  const float4* s = g == 0 ? w0 : g == 1 ? w1 : g == 2 ? w2 : w3;
  float4 v = s[i & 0x3FFFF];
  unsigned long long p = (unsigned long long)f2bf(v.x) |
                         ((unsigned long long)f2bf(v.y) << 16) |
                         ((unsigned long long)f2bf(v.z) << 32) |
                         ((unsigned long long)f2bf(v.w) << 48);
  dst[i] = p;
}

__global__ __launch_bounds__(256) void conv_wiT_kernel(
    const float* __restrict__ w0, const float* __restrict__ w1,
    const float* __restrict__ w2, const float* __restrict__ w3,
    unsigned short* __restrict__ dst) {
  __shared__ unsigned short ls[64][72];
  int bid = blockIdx.x;                 // 0..1023 : 4 gates x 16x16 tiles
  int g = bid >> 8;
  int t2 = bid & 255;
  int tj = t2 & 15, tk = t2 >> 4;
  const float* W = g == 0 ? w0 : g == 1 ? w1 : g == 2 ? w2 : w3;
  int k0 = tk * 64, j0 = tj * 64;
  int ty = threadIdx.x >> 6, tx = threadIdx.x & 63;
#pragma unroll
  for (int r = 0; r < 16; ++r) {
    int k = k0 + ty * 16 + r;
    ls[tx][ty * 16 + r] = f2bf(W[k * 1024 + j0 + tx]);  // ls[j_local][k_local]
  }
  __syncthreads();
#pragma unroll
  for (int r = 0; r < 16; ++r) {
    int jl = ty * 16 + r;
    dst[(size_t)(g * 1024 + j0 + jl) * 1024 + k0 + tx] = ls[jl][tx];
  }
}

__global__ __launch_bounds__(256) void conv_bias_kernel(
    const float* __restrict__ b0, const float* __restrict__ b1,
    const float* __restrict__ b2, const float* __restrict__ b3,
    float* __restrict__ dst) {
  int i = blockIdx.x * 256 + threadIdx.x;  // 0..4095
  const float* s = (i >> 10) == 0 ? b0 : (i >> 10) == 1 ? b1 : (i >> 10) == 2 ? b2 : b3;
  dst[i] = s[i & 1023];
}

__global__ __launch_bounds__(256) void conv_x_kernel(
    const float4* __restrict__ src, unsigned long long* __restrict__ dst, int n4) {
  int i = blockIdx.x * 256 + threadIdx.x;
  if (i < n4) {
    float4 v = src[i];
    dst[i] = (unsigned long long)f2bf(v.x) |
             ((unsigned long long)f2bf(v.y) << 16) |
             ((unsigned long long)f2bf(v.z) << 32) |
             ((unsigned long long)f2bf(v.w) << 48);
  }
}

// ---------------- input-projection GEMM ----------------
// 256x256 tile, BK=64, 16 K-tiles, 512 thr / 8 waves (2m x 4n), acc[8][4].
// Guide's minimum-2-phase recipe (T3 box): per K-tile {STAGE(next);
// ds_read+MFMA (2 kss sub-phases); vmcnt(0); barrier} -- ONE barrier and
// ONE vmcnt per 64 MFMA/wave (vs per 32 at BK=32): halves the serial-chain
// tax diagnosed at rounds 6/9 (both 43% MfmaUtil). LDS 2 x 64KB dbuf,
// swz-swizzled. Epilogue: two 128-col passes via [256][136] LDS bounce,
// NON-TEMPORAL 16B stores (kills ~0.9GB C write-allocate HBM fetch).
// XCD map: XCD x owns bn in {2x,2x+1} -> 1MB B-panels L2-resident.
__global__ __launch_bounds__(512, 2) void xproj_gemm_kernel(
    const unsigned short* __restrict__ A,   // [Mc][1024]
    const unsigned short* __restrict__ Bt,  // [4096][1024]
    unsigned short* __restrict__ C,         // [Mc][4096]
    int Mc) {
  __shared__ __align__(16) unsigned short smem[2][2][256 * 64];  // 128 KB
  int xcd = blockIdx.x & 7;               // HW round-robin block->XCD
  int i5 = blockIdx.x >> 3;
  int bn = xcd * 2 + (i5 & 1);            // 2 B-panels per XCD (1MB, L2)
  int bm = i5 >> 1;
  int m0 = bm * 256, n0 = bn * 256;
  int tid = threadIdx.x, w = tid >> 6, lane = tid & 63;
  int wm = w >> 2, wn = w & 3;
  int l15 = lane & 15, l4 = lane >> 4;

  f32x4 acc[8][4];
#pragma unroll
  for (int i = 0; i < 8; ++i)
#pragma unroll
    for (int j = 0; j < 4; ++j) acc[i][j] = (f32x4)0.f;

  auto stage = [&](int buf, int kt) {     // 8 gload16/thread, linear LDS dest
    int kk = kt * 64;
#pragma unroll
    for (int u = 0; u < 4; ++u) {
      int cid = u * 512 + tid;
      int r = cid >> 3, s = cid & 7;            // r: 0..255, slot: 0..7
      int sk = kk + ((s ^ (r & 7)) << 3);       // inverse-swizzled source
      gload16(&A[(size_t)(m0 + r) * 1024 + sk],
              &smem[buf][0][(u * 512 + w * 64) * 8]);
    }
#pragma unroll
    for (int u = 0; u < 4; ++u) {
      int cid = u * 512 + tid;
      int r = cid >> 3, s = cid & 7;
      int sk = kk + ((s ^ (r & 7)) << 3);
      gload16(&Bt[(size_t)(n0 + r) * 1024 + sk],
              &smem[buf][1][(u * 512 + w * 64) * 8]);
    }
  };

  // prologue: buffer 0 staged and certified
  stage(0, 0);
  asm volatile("s_waitcnt vmcnt(0)" ::: "memory");
  __builtin_amdgcn_sched_barrier(0);
  __builtin_amdgcn_s_barrier();
  __builtin_amdgcn_sched_barrier(0);

  int cur = 0;
  for (int t = 0; t < 16; ++t) {
    if (t < 15) stage(cur ^ 1, t + 1);    // issue-early; buf^1 reads certified
                                          // at the t-1 barrier (lgkm-before-bar)
#pragma unroll
    for (int kss = 0; kss < 2; ++kss) {
      bf16x8 af[8], bfr[4];
#pragma unroll
      for (int mf = 0; mf < 8; ++mf) {
        int e = (wm * 128 + mf * 16 + l15) * 64 + kss * 32 + l4 * 8;
        af[mf] = *(const bf16x8*)&smem[cur][0][swz(e)];
      }
#pragma unroll
      for (int nf = 0; nf < 4; ++nf) {
        int e = (wn * 64 + nf * 16 + l15) * 64 + kss * 32 + l4 * 8;
        bfr[nf] = *(const bf16x8*)&smem[cur][1][swz(e)];
      }
      __builtin_amdgcn_s_setprio(1);
#pragma unroll
      for (int mf = 0; mf < 8; ++mf)
#pragma unroll
        for (int nf = 0; nf < 4; ++nf)
          acc[mf][nf] = __builtin_amdgcn_mfma_f32_16x16x32_bf16(
              af[mf], bfr[nf], acc[mf][nf], 0, 0, 0);
      __builtin_amdgcn_s_setprio(0);
    }
    asm volatile("s_waitcnt vmcnt(0)" ::: "memory");  // stage(t+1) landed
    __builtin_amdgcn_sched_barrier(0);
    __builtin_amdgcn_s_barrier();         // all waves: reads done + buf^1 ready
    __builtin_amdgcn_sched_barrier(0);
    cur ^= 1;
  }

  // ---- epilogue: acc -> LDS (bf16) -> nt 16B stores, 2 col-halves ----
  unsigned short* lsC = &smem[0][0][0];   // [256][136] = 69632 B
#pragma unroll
  for (int h = 0; h < 2; ++h) {
    __syncthreads();                      // prev phase reads done
    if ((wn >> 1) == h) {                 // waves owning cols [h*128, +128)
#pragma unroll
      for (int mf = 0; mf < 8; ++mf)
#pragma unroll
        for (int nf = 0; nf < 4; ++nf)
#pragma unroll
          for (int r = 0; r < 4; ++r) {
            int row = wm * 128 + mf * 16 + l4 * 4 + r;
            int col = (wn & 1) * 64 + nf * 16 + l15;
            lsC[row * 136 + col] = f2bf(acc[mf][nf][r]);
          }
    }
    __syncthreads();
#pragma unroll
    for (int u = 0; u < 8; ++u) {
      int chunk = u * 512 + tid;      // 0..4095 : 256 rows x 16 chunks of 16B
      int row = chunk >> 4, c8 = chunk & 15;
      u32x4 v = *(const u32x4*)&lsC[row * 136 + c8 * 8];
      __builtin_nontemporal_store(
          v, (u32x4*)&C[(size_t)(m0 + row) * 4096 + n0 + h * 128 + c8 * 8]);
    }
  }
}

// ---------------- fused LSTM step (per-step launch) ----------------
// Tile (32 batch x 64 hidden x 4 gates), 256 threads / 4 waves, 72KB LDS
// -> grid 512 = 2 blocks/CU (decorrelated barrier groups per SIMD).
// A-rows [b_half][gate][b_lo]; XCD map: XCD x owns bb in {4x..4x+3} (1MB Wh)
// + all bj (2MB hT) -> L2-resident staging. Single-barrier 3-buffer
// pipeline, counted vmcnt (6-load stages). out_h/out_ht/out_ct stores are
// NON-TEMPORAL (write-once streams; avoids write-allocate fills).
__global__ __launch_bounds__(256) void lstm_step_kernel(
    const unsigned short* __restrict__ Wh,   // [4096][1024]
    const unsigned short* __restrict__ hT,   // [1024][1024]  hT[j][k]=h[k][j]
    const unsigned short* __restrict__ Xp,   // [1024][4096]  this step's x-proj
    const float* __restrict__ bias,          // [4096]
    float* __restrict__ cst,                 // [1024*1024] fp32 cell state
    float* __restrict__ out_h,               // d_out + t*1M
    float* __restrict__ out_ht,              // d_out + T*1M
    float* __restrict__ out_ct,              // d_out + T*1M + 1M
    unsigned short* __restrict__ hT_next,    // other hT buffer
    int isLast) {
  __shared__ unsigned short lsA[3][128 * 64];  // [b_half][gate][b_lo] x 64k
  __shared__ unsigned short lsB[3][64 * 64];
  int bx = blockIdx.x;
  int xcd = bx & 7, idx = bx >> 3;             // idx in [0,64)
  int bb = xcd * 4 + (idx & 3);                // [0,32): XCD-local Wh slice
  int bj = idx >> 2;                           // [0,16)
  int b0 = bb * 32, j0 = bj * 64;
  int tid = threadIdx.x, w = tid >> 6, lane = tid & 63;
  int wm = w >> 1, wn = w & 1;
  int l15 = lane & 15, l4 = lane >> 4;
  int bbase = b0 + wm * 16 + l4 * 4;

  // ---- prefetch epilogue operands (issued first -> oldest in vmcnt FIFO;
  //      it0's vmcnt(6) drains them along with stage(0)) ----
  float bias_pre[4][2];
  float c_pre[2][4];
  unsigned short xp_pre[4][2][4];
#pragma unroll
  for (int n = 0; n < 2; ++n) {
    int j = j0 + wn * 32 + n * 16 + l15;
#pragma unroll
    for (int g = 0; g < 4; ++g) bias_pre[g][n] = bias[g * 1024 + j];
#pragma unroll
    for (int r = 0; r < 4; ++r) {
      c_pre[n][r] = cst[(size_t)(bbase + r) * 1024 + j];
#pragma unroll
      for (int g = 0; g < 4; ++g)
        xp_pre[g][n][r] = Xp[(size_t)(bbase + r) * 4096 + g * 1024 + j];
    }
  }

  f32x4 acc[4][2];
#pragma unroll
  for (int g = 0; g < 4; ++g)
#pragma unroll
    for (int n = 0; n < 2; ++n) acc[g][n] = (f32x4)0.f;

  auto stage = [&](int buf, int kk) {          // 6 gload16 per thread
#pragma unroll
    for (int ld = 0; ld < 4; ++ld) {
      int cid = ld * 256 + tid;
      int r = cid >> 3, kc = (cid & 7) * 8;    // r: 0..127 local A-row
      int sk = kk + (kc ^ ((r & 7) << 3));
      // local row r = b_half*64 + g*16 + b_lo  ->  Wh row g*1024 + b0 + b
      int grow = ((r >> 4) & 3) * 1024 + b0 + (r >> 6) * 16 + (r & 15);
      gload16(&Wh[(size_t)grow * 1024 + sk], &lsA[buf][(ld * 256 + w * 64) * 8]);
    }
#pragma unroll
    for (int u = 0; u < 2; ++u) {
      int cid = u * 256 + tid;
      int r = cid >> 3, kc = (cid & 7) * 8;    // r: 0..63
      int sk = kk + (kc ^ ((r & 7) << 3));
      gload16(&hT[(size_t)(j0 + r) * 1024 + sk], &lsB[buf][(u * 256 + w * 64) * 8]);
    }
  };
  auto compute = [&](int buf) {
    bf16x8 af[4][2], bfr[2][2];
#pragma unroll
    for (int g = 0; g < 4; ++g)
#pragma unroll
      for (int kss = 0; kss < 2; ++kss) {
        int e = (wm * 64 + g * 16 + l15) * 64 + kss * 32 + l4 * 8;
        af[g][kss] = *(const bf16x8*)&lsA[buf][swz(e)];
      }
#pragma unroll
    for (int n = 0; n < 2; ++n)
#pragma unroll
      for (int kss = 0; kss < 2; ++kss) {
        int e = (wn * 32 + n * 16 + l15) * 64 + kss * 32 + l4 * 8;
        bfr[n][kss] = *(const bf16x8*)&lsB[buf][swz(e)];
      }
    __builtin_amdgcn_s_setprio(1);
#pragma unroll
    for (int g = 0; g < 4; ++g)
#pragma unroll
      for (int n = 0; n < 2; ++n)
#pragma unroll
        for (int kss = 0; kss < 2; ++kss)
          acc[g][n] = __builtin_amdgcn_mfma_f32_16x16x32_bf16(
              af[g][kss], bfr[n][kss], acc[g][n], 0, 0, 0);
    __builtin_amdgcn_s_setprio(0);
  };

  // prologue: 2 stages in flight (48 prefetch + 12 staging = 60 <= 63)
  stage(0, 0);
  stage(1, 64);
#pragma unroll
  for (int it = 0; it < 16; ++it) {
    // my stage(it) landed (leaves stage(it+1)'s 6 loads in flight)
    if (it < 15) asm volatile("s_waitcnt vmcnt(6)" ::: "memory");
    else         asm volatile("s_waitcnt vmcnt(0)" ::: "memory");
    __builtin_amdgcn_sched_barrier(0);
    __builtin_amdgcn_s_barrier();     // stage(it) landed + prev reads retired
    __builtin_amdgcn_sched_barrier(0);
    if (it + 2 < 16) stage((it + 2) % 3, (it + 2) * 64);  // overwrite safe now
    compute(it % 3);
    asm volatile("s_waitcnt lgkmcnt(0)" ::: "memory");    // my ds_reads done
    __builtin_amdgcn_sched_barrier(0);
  }

  // epilogue: gates + cell/hidden update (operands already in registers)
#pragma unroll
  for (int n = 0; n < 2; ++n) {
    int j = j0 + wn * 32 + n * 16 + l15;
    float hn[4], cn[4];
#pragma unroll
    for (int r = 0; r < 4; ++r) {
      int b = bbase + r;
      float pi = acc[0][n][r] + bf2f(xp_pre[0][n][r]) + bias_pre[0][n];
      float pf = acc[1][n][r] + bf2f(xp_pre[1][n][r]) + bias_pre[1][n];
      float pg = acc[2][n][r] + bf2f(xp_pre[2][n][r]) + bias_pre[2][n];
      float po = acc[3][n][r] + bf2f(xp_pre[3][n][r]) + bias_pre[3][n];
      float ig = sigm(pi), fg = sigm(pf), gg = tanh_f(pg), og = sigm(po);
      float c_new = fg * c_pre[n][r] + ig * gg;
      cst[(size_t)b * 1024 + j] = c_new;
      cn[r] = c_new;
      hn[r] = og * tanh_f(c_new);
      __builtin_nontemporal_store(hn[r], &out_h[(size_t)b * 1024 + j]);
    }
    unsigned long long hp = (unsigned long long)f2bf(hn[0]) |
                            ((unsigned long long)f2bf(hn[1]) << 16) |
                            ((unsigned long long)f2bf(hn[2]) << 32) |
                            ((unsigned long long)f2bf(hn[3]) << 48);
    *(unsigned long long*)&hT_next[(size_t)j * 1024 + bbase] = hp;
    if (isLast) {
#pragma unroll
      for (int r = 0; r < 4; ++r) {
        int b = bbase + r;
        __builtin_nontemporal_store(hn[r], &out_ht[(size_t)b * 1024 + j]);
        __builtin_nontemporal_store(cn[r], &out_ct[(size_t)b * 1024 + j]);
      }
    }
  }
}

// ---------------- host ----------------
extern "C" void kernel_launch(void* const* d_in, const int* in_sizes, int n_in,
                              void* d_out, int out_size, void* d_ws, size_t ws_size,
                              hipStream_t stream) {
  const float* X   = (const float*)d_in[0];
  const float* Wii = (const float*)d_in[1];
  const float* Whi = (const float*)d_in[2];
  const float* bi  = (const float*)d_in[3];
  const float* Wif = (const float*)d_in[4];
  const float* Whf = (const float*)d_in[5];
  const float* bfv = (const float*)d_in[6];
  const float* Wig = (const float*)d_in[7];
  const float* Whg = (const float*)d_in[8];
  const float* bg  = (const float*)d_in[9];
  const float* Wio = (const float*)d_in[10];
  const float* Who = (const float*)d_in[11];
  const float* bo  = (const float*)d_in[12];
  float* out = (float*)d_out;

  char* wsp = (char*)d_ws;
  size_t off = 0;
  auto walloc = [&](size_t b) -> void* {
    void* p = wsp + off;
    off += (b + 255) & ~(size_t)255;
    return p;
  };
  unsigned short* WiT = (unsigned short*)walloc(4096ull * 1024 * 2);
  unsigned short* Wh  = (unsigned short*)walloc(4096ull * 1024 * 2);
  float* bias = (float*)walloc(4096 * 4);
  unsigned short* hT0 = (unsigned short*)walloc(1024ull * 1024 * 2);
  unsigned short* hT1 = (unsigned short*)walloc(1024ull * 1024 * 2);
  float* cbuf = (float*)walloc(1024ull * 1024 * 4);
  size_t fixed = off;

  long long avail = (long long)ws_size - (long long)fixed - (1ll << 20);
  int Tc = (int)(avail / (10ll << 20));   // 2MB Xbf + 8MB Xproj per step
  if (Tc < 1) Tc = 1;
  if (Tc > 128) Tc = 128;
  unsigned short* Xbf = (unsigned short*)walloc((size_t)Tc * 1024 * 1024 * 2);
  unsigned short* Xp  = (unsigned short*)walloc((size_t)Tc * 1024 * 4096 * 2);

  conv_wh_kernel<<<4096, 256, 0, stream>>>((const float4*)Whi, (const float4*)Whf,
                                           (const float4*)Whg, (const float4*)Who,
                                           (unsigned long long*)Wh);
  conv_wiT_kernel<<<1024, 256, 0, stream>>>(Wii, Wif, Wig, Wio, WiT);
  conv_bias_kernel<<<16, 256, 0, stream>>>(bi, bfv, bg, bo, bias);
  hipMemsetAsync(hT0, 0, 1024ull * 1024 * 2, stream);
  hipMemsetAsync(cbuf, 0, 1024ull * 1024 * 4, stream);

  for (int t0 = 0; t0 < 128; t0 += Tc) {
    int tc = (128 - t0 < Tc) ? (128 - t0) : Tc;
    int n4 = tc * 262144;
    conv_x_kernel<<<n4 / 256, 256, 0, stream>>>(
        (const float4*)(X + (size_t)t0 * 1048576),
        (unsigned long long*)Xbf, n4);
    xproj_gemm_kernel<<<tc * 64, 512, 0, stream>>>(Xbf, WiT, Xp, tc * 1024);
    for (int i = 0; i < tc; ++i) {
      int t = t0 + i;
      lstm_step_kernel<<<512, 256, 0, stream>>>(
          Wh, (t & 1) ? hT1 : hT0,
          Xp + (size_t)i * 1024 * 4096,
          bias, cbuf,
          out + (size_t)t * 1048576,
          out + 134217728ull,
          out + 135266304ull,
          (t & 1) ? hT0 : hT1,
          (t == 127) ? 1 : 0);
    }
  }
}

// Round 12
// 3361.958 us; speedup vs baseline: 1.0704x; 1.0209x over previous
//
#include <hip/hip_runtime.h>
#include <cstdint>

typedef __attribute__((ext_vector_type(8))) short bf16x8;
typedef __attribute__((ext_vector_type(4))) float f32x4;
typedef __attribute__((ext_vector_type(4))) unsigned int u32x4;

#define AS1 __attribute__((address_space(1)))
#define AS3 __attribute__((address_space(3)))

__device__ __forceinline__ unsigned short f2bf(float f) {
  unsigned int u = __builtin_bit_cast(unsigned int, f);
  return (unsigned short)((u + 0x7fffu + ((u >> 16) & 1u)) >> 16);
}
__device__ __forceinline__ float bf2f(unsigned short h) {
  unsigned int u = ((unsigned int)h) << 16;
  return __builtin_bit_cast(float, u);
}
__device__ __forceinline__ float sigm(float x) { return 1.f / (1.f + __expf(-x)); }
__device__ __forceinline__ float tanh_f(float x) {
  float e = __expf(2.f * x);          // inf-safe: e=inf -> 1, e=0 -> -1
  return 1.f - 2.f / (e + 1.f);
}
__device__ __forceinline__ void gload16(const void* g, void* l) {
  __builtin_amdgcn_global_load_lds((const AS1 unsigned int*)g, (AS3 unsigned int*)l, 16, 0, 0);
}
// XOR-swizzle for [rows][64]-bf16 tiles (8 slots of 16B per 128B row):
// slot' = slot ^ (row&7). Pre-swizzled GLOBAL source + swizzled read,
// linear LDS dest (rule #21 both-sides).
__device__ __forceinline__ int swz(int e) { return e ^ (((e >> 6) & 7) << 3); }

// ---------------- setup / conversion kernels ----------------

__global__ __launch_bounds__(256) void conv_wh_kernel(
    const float4* __restrict__ w0, const float4* __restrict__ w1,
    const float4* __restrict__ w2, const float4* __restrict__ w3,
    unsigned long long* __restrict__ dst) {
  int i = blockIdx.x * 256 + threadIdx.x;           // 0 .. 1M-1 (float4 units)
  int g = i >> 18;                                  // 262144 float4 per matrix
  const float4* s = g == 0 ? w0 : g == 1 ? w1 : g == 2 ? w2 : w3;
  float4 v = s[i & 0x3FFFF];
  unsigned long long p = (unsigned long long)f2bf(v.x) |
                         ((unsigned long long)f2bf(v.y) << 16) |
                         ((unsigned long long)f2bf(v.z) << 32) |
                         ((unsigned long long)f2bf(v.w) << 48);
  dst[i] = p;
}

__global__ __launch_bounds__(256) void conv_wiT_kernel(
    const float* __restrict__ w0, const float* __restrict__ w1,
    const float* __restrict__ w2, const float* __restrict__ w3,
    unsigned short* __restrict__ dst) {
  __shared__ unsigned short ls[64][72];
  int bid = blockIdx.x;                 // 0..1023 : 4 gates x 16x16 tiles
  int g = bid >> 8;
  int t2 = bid & 255;
  int tj = t2 & 15, tk = t2 >> 4;
  const float* W = g == 0 ? w0 : g == 1 ? w1 : g == 2 ? w2 : w3;
  int k0 = tk * 64, j0 = tj * 64;
  int ty = threadIdx.x >> 6, tx = threadIdx.x & 63;
#pragma unroll
  for (int r = 0; r < 16; ++r) {
    int k = k0 + ty * 16 + r;
    ls[tx][ty * 16 + r] = f2bf(W[k * 1024 + j0 + tx]);  // ls[j_local][k_local]
  }
  __syncthreads();
#pragma unroll
  for (int r = 0; r < 16; ++r) {
    int jl = ty * 16 + r;
    dst[(size_t)(g * 1024 + j0 + jl) * 1024 + k0 + tx] = ls[jl][tx];
  }
}

__global__ __launch_bounds__(256) void conv_bias_kernel(
    const float* __restrict__ b0, const float* __restrict__ b1,
    const float* __restrict__ b2, const float* __restrict__ b3,
    float* __restrict__ dst) {
  int i = blockIdx.x * 256 + threadIdx.x;  // 0..4095
  const float* s = (i >> 10) == 0 ? b0 : (i >> 10) == 1 ? b1 : (i >> 10) == 2 ? b2 : b3;
  dst[i] = s[i & 1023];
}

__global__ __launch_bounds__(256) void conv_x_kernel(
    const float4* __restrict__ src, unsigned long long* __restrict__ dst, int n4) {
  int i = blockIdx.x * 256 + threadIdx.x;
  if (i < n4) {
    float4 v = src[i];
    dst[i] = (unsigned long long)f2bf(v.x) |
             ((unsigned long long)f2bf(v.y) << 16) |
             ((unsigned long long)f2bf(v.z) << 32) |
             ((unsigned long long)f2bf(v.w) << 48);
  }
}

// ---------------- input-projection GEMM (4-phase half-tile ring) ----------
// 256x256 tile, BK=64, 16 K-tiles, 512 thr / 8 waves (2m x 4n), acc[8][4].
// m201-style schedule in 128KB: per K-tile 4 phases, each {counted vmcnt;
// barrier; ds_read ONE fragment group; issue ONE half-stage of t+1;
// lgkmcnt(0); setprio MFMA cluster}. Fragment rows remapped so each group
// lives in one 16KB half (af03->A0, af47->A1, bfr01->B0, bfr23->B1);
// clusters pipelined by one phase (c4 of t runs in P1 of t+1). vmcnt=6
// steady (needed half = oldest of <=4 in flight), 6/4/2/0 on last tile.
// XCD map: XCD x owns bn in {2x,2x+1} -> 1MB B-panels L2-resident.
__global__ __launch_bounds__(512) void xproj_gemm_kernel(
    const unsigned short* __restrict__ A,   // [Mc][1024]
    const unsigned short* __restrict__ Bt,  // [4096][1024]
    unsigned short* __restrict__ C,         // [Mc][4096]
    int Mc) {
  __shared__ __align__(16) unsigned short smem[2][2][256 * 64];  // 128 KB
  int xcd = blockIdx.x & 7;               // HW round-robin block->XCD
  int i5 = blockIdx.x >> 3;
  int bn = xcd * 2 + (i5 & 1);            // 2 B-panels per XCD (1MB, L2)
  int bm = i5 >> 1;
  int m0 = bm * 256, n0 = bn * 256;
  int tid = threadIdx.x, w = tid >> 6, lane = tid & 63;
  int wm = w >> 2, wn = w & 3;
  int l15 = lane & 15, l4 = lane >> 4;

  f32x4 acc[8][4];
#pragma unroll
  for (int i = 0; i < 8; ++i)
#pragma unroll
    for (int j = 0; j < 4; ++j) acc[i][j] = (f32x4)0.f;

  // half-stage X of K-tile kt into buf: X: 0=A rows0-127, 1=B rows0-127,
  // 2=A rows128-255, 3=B rows128-255. 2 gload16/thread.
  auto stageHalf = [&](int buf, int kt, int X) {
    int kk = kt * 64;
    unsigned short* dst = &smem[buf][X & 1][0];
    const unsigned short* src = (X & 1) ? Bt : A;
    int gbase = (X & 1) ? n0 : m0;
    int r0 = (X >> 1) * 128;
#pragma unroll
    for (int u = 0; u < 2; ++u) {
      int cid = u * 512 + tid;
      int rl = r0 + (cid >> 3), s = cid & 7;
      int sk = kk + ((s ^ (rl & 7)) << 3);       // inverse-swizzled source
      gload16(&src[(size_t)(gbase + rl) * 1024 + sk],
              &dst[r0 * 64 + (u * 512 + w * 64) * 8]);
    }
  };
  // fragment-group reads (each group entirely within one half)
  auto rdA = [&](int buf, int lo, bf16x8 (&arr)[4][2]) {
#pragma unroll
    for (int mf = 0; mf < 4; ++mf)
#pragma unroll
      for (int kss = 0; kss < 2; ++kss) {
        int row = lo * 128 + wm * 64 + mf * 16 + l15;
        arr[mf][kss] =
            *(const bf16x8*)&smem[buf][0][swz(row * 64 + kss * 32 + l4 * 8)];
      }
  };
  auto rdB = [&](int buf, int lo, bf16x8 (&arr)[2][2]) {
#pragma unroll
    for (int nf = 0; nf < 2; ++nf)
#pragma unroll
      for (int kss = 0; kss < 2; ++kss) {
        int row = lo * 128 + wn * 32 + nf * 16 + l15;
        arr[nf][kss] =
            *(const bf16x8*)&smem[buf][1][swz(row * 64 + kss * 32 + l4 * 8)];
      }
  };

  bf16x8 af03[4][2], af47[4][2], bfr01[2][2], bfr23[2][2];

  // prologue: all 4 halves of tile 0 (8 loads outstanding)
  stageHalf(0, 0, 0); stageHalf(0, 0, 1); stageHalf(0, 0, 2); stageHalf(0, 0, 3);

  for (int t = 0; t < 16; ++t) {
    int c = t & 1;
    // ---- P1: read af03(t); stage A0(t+1); cluster c4(t-1) ----
    if (t < 15) asm volatile("s_waitcnt vmcnt(6)" ::: "memory");
    else        asm volatile("s_waitcnt vmcnt(6)" ::: "memory");
    __builtin_amdgcn_sched_barrier(0);
    __builtin_amdgcn_s_barrier();
    __builtin_amdgcn_sched_barrier(0);
    rdA(c, 0, af03);
    if (t + 1 < 16) stageHalf(c ^ 1, t + 1, 0);
    asm volatile("s_waitcnt lgkmcnt(0)" ::: "memory");
    __builtin_amdgcn_sched_barrier(0);
    if (t > 0) {
      __builtin_amdgcn_s_setprio(1);
#pragma unroll
      for (int mf = 0; mf < 4; ++mf)
#pragma unroll
        for (int nf = 0; nf < 2; ++nf)
#pragma unroll
          for (int kss = 0; kss < 2; ++kss)
            acc[4 + mf][2 + nf] = __builtin_amdgcn_mfma_f32_16x16x32_bf16(
                af47[mf][kss], bfr23[nf][kss], acc[4 + mf][2 + nf], 0, 0, 0);
      __builtin_amdgcn_s_setprio(0);
    }
    // ---- P2: read bfr01(t); stage B0(t+1); cluster c1 = af03 x bfr01 ----
    if (t < 15) asm volatile("s_waitcnt vmcnt(6)" ::: "memory");
    else        asm volatile("s_waitcnt vmcnt(4)" ::: "memory");
    __builtin_amdgcn_sched_barrier(0);
    __builtin_amdgcn_s_barrier();
    __builtin_amdgcn_sched_barrier(0);
    rdB(c, 0, bfr01);
    if (t + 1 < 16) stageHalf(c ^ 1, t + 1, 1);
    asm volatile("s_waitcnt lgkmcnt(0)" ::: "memory");
    __builtin_amdgcn_sched_barrier(0);
    __builtin_amdgcn_s_setprio(1);
#pragma unroll
    for (int mf = 0; mf < 4; ++mf)
#pragma unroll
      for (int nf = 0; nf < 2; ++nf)
#pragma unroll
        for (int kss = 0; kss < 2; ++kss)
          acc[mf][nf] = __builtin_amdgcn_mfma_f32_16x16x32_bf16(
              af03[mf][kss], bfr01[nf][kss], acc[mf][nf], 0, 0, 0);
    __builtin_amdgcn_s_setprio(0);
    // ---- P3: read af47(t); stage A1(t+1); cluster c2 = af47 x bfr01 ----
    if (t < 15) asm volatile("s_waitcnt vmcnt(6)" ::: "memory");
    else        asm volatile("s_waitcnt vmcnt(2)" ::: "memory");
    __builtin_amdgcn_sched_barrier(0);
    __builtin_amdgcn_s_barrier();
    __builtin_amdgcn_sched_barrier(0);
    rdA(c, 1, af47);
    if (t + 1 < 16) stageHalf(c ^ 1, t + 1, 2);
    asm volatile("s_waitcnt lgkmcnt(0)" ::: "memory");
    __builtin_amdgcn_sched_barrier(0);
    __builtin_amdgcn_s_setprio(1);
#pragma unroll
    for (int mf = 0; mf < 4; ++mf)
#pragma unroll
      for (int nf = 0; nf < 2; ++nf)
#pragma unroll
        for (int kss = 0; kss < 2; ++kss)
          acc[4 + mf][nf] = __builtin_amdgcn_mfma_f32_16x16x32_bf16(
              af47[mf][kss], bfr01[nf][kss], acc[4 + mf][nf], 0, 0, 0);
    __builtin_amdgcn_s_setprio(0);
    // ---- P4: read bfr23(t); stage B1(t+1); cluster c3 = af03 x bfr23 ----
    if (t < 15) asm volatile("s_waitcnt vmcnt(6)" ::: "memory");
    else        asm volatile("s_waitcnt vmcnt(0)" ::: "memory");
    __builtin_amdgcn_sched_barrier(0);
    __builtin_amdgcn_s_barrier();
    __builtin_amdgcn_sched_barrier(0);
    rdB(c, 1, bfr23);
    if (t + 1 < 16) stageHalf(c ^ 1, t + 1, 3);
    asm volatile("s_waitcnt lgkmcnt(0)" ::: "memory");
    __builtin_amdgcn_sched_barrier(0);
    __builtin_amdgcn_s_setprio(1);
#pragma unroll
    for (int mf = 0; mf < 4; ++mf)
#pragma unroll
      for (int nf = 0; nf < 2; ++nf)
#pragma unroll
        for (int kss = 0; kss < 2; ++kss)
          acc[mf][2 + nf] = __builtin_amdgcn_mfma_f32_16x16x32_bf16(
              af03[mf][kss], bfr23[nf][kss], acc[mf][2 + nf], 0, 0, 0);
    __builtin_amdgcn_s_setprio(0);
  }
  // trailing cluster c4 of tile 15
  {
    __builtin_amdgcn_s_setprio(1);
#pragma unroll
    for (int mf = 0; mf < 4; ++mf)
#pragma unroll
      for (int nf = 0; nf < 2; ++nf)
#pragma unroll
        for (int kss = 0; kss < 2; ++kss)
          acc[4 + mf][2 + nf] = __builtin_amdgcn_mfma_f32_16x16x32_bf16(
              af47[mf][kss], bfr23[nf][kss], acc[4 + mf][2 + nf], 0, 0, 0);
    __builtin_amdgcn_s_setprio(0);
  }

  // ---- epilogue: acc -> LDS (bf16) -> nt 16B stores, 2 col-halves ----
  // row_local(mf) = (mf<4 ? wm*64+mf*16 : 128+wm*64+(mf-4)*16) + l4*4+r
  // col half h holds nf in {2h, 2h+1}: col_in_half = wn*32 + (nf&1)*16 + l15
  unsigned short* lsC = &smem[0][0][0];   // [256][136] = 69632 B
#pragma unroll
  for (int h = 0; h < 2; ++h) {
    __syncthreads();                      // prev phase reads done
#pragma unroll
    for (int mf = 0; mf < 8; ++mf)
#pragma unroll
      for (int f = 0; f < 2; ++f) {
        int nf = h * 2 + f;
        int rowl = (mf < 4 ? wm * 64 + mf * 16 : 128 + wm * 64 + (mf - 4) * 16)
                   + l4 * 4;
        int coll = wn * 32 + f * 16 + l15;
#pragma unroll
        for (int r = 0; r < 4; ++r)
          lsC[(rowl + r) * 136 + coll] = f2bf(acc[mf][nf][r]);
      }
    __syncthreads();
#pragma unroll
    for (int u = 0; u < 8; ++u) {
      int chunk = u * 512 + tid;      // 0..4095 : 256 rows x 16 chunks of 16B
      int row = chunk >> 4, c8 = chunk & 15;
      u32x4 v = *(const u32x4*)&lsC[row * 136 + c8 * 8];
      __builtin_nontemporal_store(
          v, (u32x4*)&C[(size_t)(m0 + row) * 4096 + n0 + h * 128 + c8 * 8]);
    }
  }
}

// ---------------- fused LSTM step (per-step launch) ----------------
// Tile (32 batch x 64 hidden x 4 gates), 256 threads / 4 waves, 72KB LDS
// -> grid 512 = 2 blocks/CU (decorrelated barrier groups per SIMD).
// A-rows [b_half][gate][b_lo]; XCD map: XCD x owns bb in {4x..4x+3} (1MB Wh)
// + all bj (2MB hT) -> L2-resident staging. Single-barrier 3-buffer
// pipeline, counted vmcnt (6-load stages). out_h/out_ht/out_ct stores are
// NON-TEMPORAL (write-once streams). UNCHANGED from round 11.
__global__ __launch_bounds__(256) void lstm_step_kernel(
    const unsigned short* __restrict__ Wh,   // [4096][1024]
    const unsigned short* __restrict__ hT,   // [1024][1024]  hT[j][k]=h[k][j]
    const unsigned short* __restrict__ Xp,   // [1024][4096]  this step's x-proj
    const float* __restrict__ bias,          // [4096]
    float* __restrict__ cst,                 // [1024*1024] fp32 cell state
    float* __restrict__ out_h,               // d_out + t*1M
    float* __restrict__ out_ht,              // d_out + T*1M
    float* __restrict__ out_ct,              // d_out + T*1M + 1M
    unsigned short* __restrict__ hT_next,    // other hT buffer
    int isLast) {
  __shared__ unsigned short lsA[3][128 * 64];  // [b_half][gate][b_lo] x 64k
  __shared__ unsigned short lsB[3][64 * 64];
  int bx = blockIdx.x;
  int xcd = bx & 7, idx = bx >> 3;             // idx in [0,64)
  int bb = xcd * 4 + (idx & 3);                // [0,32): XCD-local Wh slice
  int bj = idx >> 2;                           // [0,16)
  int b0 = bb * 32, j0 = bj * 64;
  int tid = threadIdx.x, w = tid >> 6, lane = tid & 63;
  int wm = w >> 1, wn = w & 1;
  int l15 = lane & 15, l4 = lane >> 4;
  int bbase = b0 + wm * 16 + l4 * 4;

  // ---- prefetch epilogue operands (issued first -> oldest in vmcnt FIFO;
  //      it0's vmcnt(6) drains them along with stage(0)) ----
  float bias_pre[4][2];
  float c_pre[2][4];
  unsigned short xp_pre[4][2][4];
#pragma unroll
  for (int n = 0; n < 2; ++n) {
    int j = j0 + wn * 32 + n * 16 + l15;
#pragma unroll
    for (int g = 0; g < 4; ++g) bias_pre[g][n] = bias[g * 1024 + j];
#pragma unroll
    for (int r = 0; r < 4; ++r) {
      c_pre[n][r] = cst[(size_t)(bbase + r) * 1024 + j];
#pragma unroll
      for (int g = 0; g < 4; ++g)
        xp_pre[g][n][r] = Xp[(size_t)(bbase + r) * 4096 + g * 1024 + j];
    }
  }

  f32x4 acc[4][2];
#pragma unroll
  for (int g = 0; g < 4; ++g)
#pragma unroll
    for (int n = 0; n < 2; ++n) acc[g][n] = (f32x4)0.f;

  auto stage = [&](int buf, int kk) {          // 6 gload16 per thread
#pragma unroll
    for (int ld = 0; ld < 4; ++ld) {
      int cid = ld * 256 + tid;
      int r = cid >> 3, kc = (cid & 7) * 8;    // r: 0..127 local A-row
      int sk = kk + (kc ^ ((r & 7) << 3));
      // local row r = b_half*64 + g*16 + b_lo  ->  Wh row g*1024 + b0 + b
      int grow = ((r >> 4) & 3) * 1024 + b0 + (r >> 6) * 16 + (r & 15);
      gload16(&Wh[(size_t)grow * 1024 + sk], &lsA[buf][(ld * 256 + w * 64) * 8]);
    }
#pragma unroll
    for (int u = 0; u < 2; ++u) {
      int cid = u * 256 + tid;
      int r = cid >> 3, kc = (cid & 7) * 8;    // r: 0..63
      int sk = kk + (kc ^ ((r & 7) << 3));
      gload16(&hT[(size_t)(j0 + r) * 1024 + sk], &lsB[buf][(u * 256 + w * 64) * 8]);
    }
  };
  auto compute = [&](int buf) {
    bf16x8 af[4][2], bfr[2][2];
#pragma unroll
    for (int g = 0; g < 4; ++g)
#pragma unroll
      for (int kss = 0; kss < 2; ++kss) {
        int e = (wm * 64 + g * 16 + l15) * 64 + kss * 32 + l4 * 8;
        af[g][kss] = *(const bf16x8*)&lsA[buf][swz(e)];
      }
#pragma unroll
    for (int n = 0; n < 2; ++n)
#pragma unroll
      for (int kss = 0; kss < 2; ++kss) {
        int e = (wn * 32 + n * 16 + l15) * 64 + kss * 32 + l4 * 8;
        bfr[n][kss] = *(const bf16x8*)&lsB[buf][swz(e)];
      }
    __builtin_amdgcn_s_setprio(1);
#pragma unroll
    for (int g = 0; g < 4; ++g)
#pragma unroll
      for (int n = 0; n < 2; ++n)
#pragma unroll
        for (int kss = 0; kss < 2; ++kss)
          acc[g][n] = __builtin_amdgcn_mfma_f32_16x16x32_bf16(
              af[g][kss], bfr[n][kss], acc[g][n], 0, 0, 0);
    __builtin_amdgcn_s_setprio(0);
  };

  // prologue: 2 stages in flight (48 prefetch + 12 staging = 60 <= 63)
  stage(0, 0);
  stage(1, 64);
#pragma unroll
  for (int it = 0; it < 16; ++it) {
    // my stage(it) landed (leaves stage(it+1)'s 6 loads in flight)
    if (it < 15) asm volatile("s_waitcnt vmcnt(6)" ::: "memory");
    else         asm volatile("s_waitcnt vmcnt(0)" ::: "memory");
    __builtin_amdgcn_sched_barrier(0);
    __builtin_amdgcn_s_barrier();     // stage(it) landed + prev reads retired
    __builtin_amdgcn_sched_barrier(0);
    if (it + 2 < 16) stage((it + 2) % 3, (it + 2) * 64);  // overwrite safe now
    compute(it % 3);
    asm volatile("s_waitcnt lgkmcnt(0)" ::: "memory");    // my ds_reads done
    __builtin_amdgcn_sched_barrier(0);
  }

  // epilogue: gates + cell/hidden update (operands already in registers)
#pragma unroll
  for (int n = 0; n < 2; ++n) {
    int j = j0 + wn * 32 + n * 16 + l15;
    float hn[4], cn[4];
#pragma unroll
    for (int r = 0; r < 4; ++r) {
      int b = bbase + r;
      float pi = acc[0][n][r] + bf2f(xp_pre[0][n][r]) + bias_pre[0][n];
      float pf = acc[1][n][r] + bf2f(xp_pre[1][n][r]) + bias_pre[1][n];
      float pg = acc[2][n][r] + bf2f(xp_pre[2][n][r]) + bias_pre[2][n];
      float po = acc[3][n][r] + bf2f(xp_pre[3][n][r]) + bias_pre[3][n];
      float ig = sigm(pi), fg = sigm(pf), gg = tanh_f(pg), og = sigm(po);
      float c_new = fg * c_pre[n][r] + ig * gg;
      cst[(size_t)b * 1024 + j] = c_new;
      cn[r] = c_new;
      hn[r] = og * tanh_f(c_new);
      __builtin_nontemporal_store(hn[r], &out_h[(size_t)b * 1024 + j]);
    }
    unsigned long long hp = (unsigned long long)f2bf(hn[0]) |
                            ((unsigned long long)f2bf(hn[1]) << 16) |
                            ((unsigned long long)f2bf(hn[2]) << 32) |
                            ((unsigned long long)f2bf(hn[3]) << 48);
    *(unsigned long long*)&hT_next[(size_t)j * 1024 + bbase] = hp;
    if (isLast) {
#pragma unroll
      for (int r = 0; r < 4; ++r) {
        int b = bbase + r;
        __builtin_nontemporal_store(hn[r], &out_ht[(size_t)b * 1024 + j]);
        __builtin_nontemporal_store(cn[r], &out_ct[(size_t)b * 1024 + j]);
      }
    }
  }
}

// ---------------- host ----------------
extern "C" void kernel_launch(void* const* d_in, const int* in_sizes, int n_in,
                              void* d_out, int out_size, void* d_ws, size_t ws_size,
                              hipStream_t stream) {
  const float* X   = (const float*)d_in[0];
  const float* Wii = (const float*)d_in[1];
  const float* Whi = (const float*)d_in[2];
  const float* bi  = (const float*)d_in[3];
  const float* Wif = (const float*)d_in[4];
  const float* Whf = (const float*)d_in[5];
  const float* bfv = (const float*)d_in[6];
  const float* Wig = (const float*)d_in[7];
  const float* Whg = (const float*)d_in[8];
  const float* bg  = (const float*)d_in[9];
  const float* Wio = (const float*)d_in[10];
  const float* Who = (const float*)d_in[11];
  const float* bo  = (const float*)d_in[12];
  float* out = (float*)d_out;

  char* wsp = (char*)d_ws;
  size_t off = 0;
  auto walloc = [&](size_t b) -> void* {
    void* p = wsp + off;
    off += (b + 255) & ~(size_t)255;
    return p;
  };
  unsigned short* WiT = (unsigned short*)walloc(4096ull * 1024 * 2);
  unsigned short* Wh  = (unsigned short*)walloc(4096ull * 1024 * 2);
  float* bias = (float*)walloc(4096 * 4);
  unsigned short* hT0 = (unsigned short*)walloc(1024ull * 1024 * 2);
  unsigned short* hT1 = (unsigned short*)walloc(1024ull * 1024 * 2);
  float* cbuf = (float*)walloc(1024ull * 1024 * 4);
  size_t fixed = off;

  long long avail = (long long)ws_size - (long long)fixed - (1ll << 20);
  int Tc = (int)(avail / (10ll << 20));   // 2MB Xbf + 8MB Xproj per step
  if (Tc < 1) Tc = 1;
  if (Tc > 128) Tc = 128;
  unsigned short* Xbf = (unsigned short*)walloc((size_t)Tc * 1024 * 1024 * 2);
  unsigned short* Xp  = (unsigned short*)walloc((size_t)Tc * 1024 * 4096 * 2);

  conv_wh_kernel<<<4096, 256, 0, stream>>>((const float4*)Whi, (const float4*)Whf,
                                           (const float4*)Whg, (const float4*)Who,
                                           (unsigned long long*)Wh);
  conv_wiT_kernel<<<1024, 256, 0, stream>>>(Wii, Wif, Wig, Wio, WiT);
  conv_bias_kernel<<<16, 256, 0, stream>>>(bi, bfv, bg, bo, bias);
  hipMemsetAsync(hT0, 0, 1024ull * 1024 * 2, stream);
  hipMemsetAsync(cbuf, 0, 1024ull * 1024 * 4, stream);

  for (int t0 = 0; t0 < 128; t0 += Tc) {
    int tc = (128 - t0 < Tc) ? (128 - t0) : Tc;
    int n4 = tc * 262144;
    conv_x_kernel<<<n4 / 256, 256, 0, stream>>>(
        (const float4*)(X + (size_t)t0 * 1048576),
        (unsigned long long*)Xbf, n4);
    xproj_gemm_kernel<<<tc * 64, 512, 0, stream>>>(Xbf, WiT, Xp, tc * 1024);
    for (int i = 0; i < tc; ++i) {
      int t = t0 + i;
      lstm_step_kernel<<<512, 256, 0, stream>>>(
          Wh, (t & 1) ? hT1 : hT0,
          Xp + (size_t)i * 1024 * 4096,
          bias, cbuf,
          out + (size_t)t * 1048576,
          out + 134217728ull,
          out + 135266304ull,
          (t & 1) ? hT0 : hT1,
          (t == 127) ? 1 : 0);
    }
  }
}